// Round 3
// baseline (118.252 us; speedup 1.0000x reference)
//
#include <hip/hip_runtime.h>
#include <math.h>

// Problem constants (match reference setup_inputs)
#define VOCAB   32000
#define D_MODEL 512
#define BATCH   8
#define SEQ     4096

// -log2(10000)/256 : invfreq(d) = 10000^(-d/256) = exp2f(d * NEG_L2_1E4_O256)
#define NEG_L2_1E4_O256 (-13.287712379549449f / 256.0f)
#define INV_2PI 0.15915494309189535f

// Native clang vector type: required by __builtin_nontemporal_store
// (HIP_vector_type float4 is a class and is rejected).
typedef float v4f __attribute__((ext_vector_type(4)));

// 256-thread blocks; each block covers TWO sequence positions:
//   s = 2*blockIdx.x + (threadIdx.x >> 7); column tid = threadIdx.x & 127.
// Each wave (64 lanes) lies entirely within one s -> token loads stay
// wave-uniform (scalar), gathers/stores stay 1 KiB-contiguous per wave.
// PE for (s,d) computed once in registers, reused across all 8 batches.
// sin/cos via HW v_sin_f32/v_cos_f32 (input in revolutions, v_fract for
// range reduction) -- ~3x fewer VALU inst than libm sinf/cosf; error ~5e-4
// vs 0.124 threshold. Output stores are nontemporal: written once, never
// read -> keep L2/L3 for gathered table rows instead.
__global__ __launch_bounds__(256) void emb_pe_kernel(
    const int*   __restrict__ tokens,   // [BATCH, SEQ] int32
    const float* __restrict__ table,    // [VOCAB, D_MODEL] fp32
    float*       __restrict__ out)      // [BATCH, SEQ, D_MODEL] fp32
{
    const int s   = (blockIdx.x << 1) | (threadIdx.x >> 7);
    const int tid = threadIdx.x & 127;   // float4 column 0..127
    const int d0  = tid << 2;            // first of 4 d-indices

    // --- positional encoding for (s, d0..d0+3) ---
    const float sf = (float)s;
    float pe[4];
#pragma unroll
    for (int j = 0; j < 4; ++j) {
        const int d = d0 + j;
        // angle/2pi in revolutions; fract-reduce for v_sin/v_cos
        const float invf = exp2f((float)d * NEG_L2_1E4_O256);
        float rev = sf * invf * INV_2PI;
        rev -= floorf(rev);              // v_fract_f32
        // d0 is even, so parity of d == parity of j (compile-time select)
        pe[j] = (j & 1) ? __builtin_amdgcn_cosf(rev)
                        : __builtin_amdgcn_sinf(rev);
    }

    const v4f* tbl4 = (const v4f*)table;
    v4f*       out4 = (v4f*)out;

    // Prefetch all 8 tokens (wave-uniform -> scalar loads)
    int tok[BATCH];
#pragma unroll
    for (int b = 0; b < BATCH; ++b)
        tok[b] = tokens[b * SEQ + s];

#pragma unroll
    for (int b = 0; b < BATCH; ++b) {
        v4f e = tbl4[tok[b] * (D_MODEL / 4) + tid];
        e.x += pe[0];
        e.y += pe[1];
        e.z += pe[2];
        e.w += pe[3];
        __builtin_nontemporal_store(
            e, &out4[((size_t)b * SEQ + s) * (D_MODEL / 4) + tid]);
    }
}

extern "C" void kernel_launch(void* const* d_in, const int* in_sizes, int n_in,
                              void* d_out, int out_size, void* d_ws, size_t ws_size,
                              hipStream_t stream) {
    const int*   tokens = (const int*)d_in[0];    // [8,4096] int32
    const float* table  = (const float*)d_in[1];  // [32000,512] fp32
    float*       out    = (float*)d_out;          // [8,4096,512] fp32

    emb_pe_kernel<<<SEQ / 2, 256, 0, stream>>>(tokens, table, out);
}